// Round 8
// baseline (132.540 us; speedup 1.0000x reference)
//
#include <hip/hip_runtime.h>

typedef unsigned long long u64;

#define CSC 2.8853900817779268f   // 2*log2(e): tanh(x) = 1 - 2/(exp2(x*CSC)+1)
#define NBIN 4096
#define CAPC 128                  // per-chunk candidate cap
#define NCH  8                    // target chunks per row
#define BT   16
#define MAXJ4 8                   // select1 supports CH <= 8*1024*4/4 = 8192

// ---------- sortable key packing ----------
__device__ __forceinline__ unsigned ord32(float f) {
  unsigned u = __float_as_uint(f);
  return (u & 0x80000000u) ? ~u : (u | 0x80000000u);
}
// max-key: descending score, ties -> ascending index (jax.lax.top_k semantics)
__device__ __forceinline__ u64 packMax(float f, int n) {
  return ((u64)ord32(f) << 32) | (unsigned)(~(unsigned)n);
}

// ================= prep: 4x4 register-tiled projection (r7, unchanged) =================
__global__ void __launch_bounds__(256)
prep_kernel(const float* __restrict__ basket, const float* __restrict__ item,
            const float* __restrict__ Wb, const float* __restrict__ Wi,
            float* __restrict__ ipE, float* __restrict__ bpE,
            int N, int B, int nItemBlk) {
  __shared__ float itS[64][64];   // [e][row]
  __shared__ float WT[64][64];    // [e][d]
  int tid = threadIdx.x;

  bool isBasket = (blockIdx.x >= nItemBlk);
  const float* src = isBasket ? basket : item;
  const float* W   = isBasket ? Wb : Wi;
  float* dst       = isBasket ? bpE : ipE;
  int r0   = isBasket ? (blockIdx.x - nItemBlk) * 64 : blockIdx.x * 64;
  int rMax = isBasket ? B : N;

  {
    int r = tid & 63, ec = (tid >> 6) * 16;
    const float4* sp = (const float4*)(src + (size_t)(r0 + r) * 64 + ec);
    bool ok = (r0 + r) < rMax;
#pragma unroll
    for (int q = 0; q < 4; ++q) {
      float4 t = ok ? sp[q] : make_float4(0.f, 0.f, 0.f, 0.f);
      itS[ec + 4 * q + 0][r] = t.x;
      itS[ec + 4 * q + 1][r] = t.y;
      itS[ec + 4 * q + 2][r] = t.z;
      itS[ec + 4 * q + 3][r] = t.w;
    }
    const float4* wp = (const float4*)(W + (size_t)r * 64 + ec);
#pragma unroll
    for (int q = 0; q < 4; ++q) {
      float4 t = wp[q];
      WT[ec + 4 * q + 0][r] = t.x;
      WT[ec + 4 * q + 1][r] = t.y;
      WT[ec + 4 * q + 2][r] = t.z;
      WT[ec + 4 * q + 3][r] = t.w;
    }
  }
  __syncthreads();

  int ti = tid & 15, td = tid >> 4;
  float acc[4][4];
#pragma unroll
  for (int i = 0; i < 4; ++i)
#pragma unroll
    for (int j = 0; j < 4; ++j) acc[i][j] = 0.f;

#pragma unroll 8
  for (int e = 0; e < 64; ++e) {
    float4 ri = *(const float4*)&itS[e][4 * ti];
    float4 wd = *(const float4*)&WT[e][4 * td];
    float rr[4] = {ri.x, ri.y, ri.z, ri.w};
    float ww[4] = {wd.x, wd.y, wd.z, wd.w};
#pragma unroll
    for (int i = 0; i < 4; ++i)
#pragma unroll
      for (int j = 0; j < 4; ++j) acc[i][j] = fmaf(rr[i], ww[j], acc[i][j]);
  }

#pragma unroll
  for (int i = 0; i < 4; ++i) {
    int gr = r0 + 4 * ti + i;
    if (gr < rMax) {
      float4 o;
      o.x = __builtin_amdgcn_exp2f(acc[i][0] * CSC);
      o.y = __builtin_amdgcn_exp2f(acc[i][1] * CSC);
      o.z = __builtin_amdgcn_exp2f(acc[i][2] * CSC);
      o.w = __builtin_amdgcn_exp2f(acc[i][3] * CSC);
      *(float4*)(dst + (size_t)gr * 64 + 4 * td) = o;
    }
  }
}

// ================= scores: 4-term rational grouping =================
// sum_{d in 4} v_d/x_d = (n01*p23 + n23*p01) / (p01*p23); x_d <= 2^23 -> den <= 2^92, safe
__global__ void __launch_bounds__(256)
scores_kernel(const float* __restrict__ ipE, const float* __restrict__ bpE,
              const float* __restrict__ v, float* __restrict__ scores, int N, int B) {
  int tid = threadIdx.x;
  int b0 = blockIdx.y * BT;
  if (b0 > B - BT) b0 = B - BT;              // duplicate-safe clamp
  int n = blockIdx.x * 256 + tid;
  if (n >= N) return;

  float ei[64];
  const float4* p = (const float4*)(ipE + (size_t)n * 64);
#pragma unroll
  for (int i = 0; i < 16; ++i) {
    float4 t = p[i];
    ei[4 * i] = t.x; ei[4 * i + 1] = t.y; ei[4 * i + 2] = t.z; ei[4 * i + 3] = t.w;
  }

  double sv = 0.0;
#pragma unroll
  for (int d = 0; d < 64; ++d) sv += (double)v[d];   // uniform -> s_load

#pragma unroll 4
  for (int b = 0; b < BT; ++b) {
    const float* eb = bpE + (size_t)(b0 + b) * 64;   // uniform -> s_load
    double acc = 0.0;
#pragma unroll
    for (int g = 0; g < 8; ++g) {                    // 8 d per group, f64 fold per group
      float gs;
#pragma unroll
      for (int h = 0; h < 2; ++h) {                  // two 4-term subgroups
        int q0 = g * 8 + h * 4;
        float x0 = fmaf(eb[q0 + 0], ei[q0 + 0], 1.0f);
        float x1 = fmaf(eb[q0 + 1], ei[q0 + 1], 1.0f);
        float x2 = fmaf(eb[q0 + 2], ei[q0 + 2], 1.0f);
        float x3 = fmaf(eb[q0 + 3], ei[q0 + 3], 1.0f);
        float p01 = x0 * x1, p23 = x2 * x3;
        float den = p01 * p23;
        float n01 = v[q0 + 0] * x1;
        n01 = fmaf(v[q0 + 1], x0, n01);
        float n23 = v[q0 + 2] * x3;
        n23 = fmaf(v[q0 + 3], x2, n23);
        float num = n01 * p23;
        num = fmaf(n23, p01, num);
        float r = __builtin_amdgcn_rcpf(den);        // 1 rcp per 4 terms
        gs = (h == 0) ? num * r : fmaf(num, r, gs);
      }
      acc += (double)gs;
    }
    scores[(size_t)(b0 + b) * N + n] = (float)(sv - 2.0 * acc);
  }
}

// ================= select phase 1: per-chunk local top/bottom-K compact =================
// Global top-K is a subset of the union of chunk-local top-Ks (rank argument).
__global__ void __launch_bounds__(256)
select1_kernel(const float* __restrict__ scores, const float* __restrict__ v,
               int* __restrict__ cnt, u64* __restrict__ candP, u64* __restrict__ candN,
               int N, int CH, int nch, int K) {
  __shared__ int lh[NBIN];
  __shared__ int part[64];
  __shared__ int hHi, hLo;
  int tid = threadIdx.x, ch = blockIdx.x, b = blockIdx.y;
  const float* row = scores + (size_t)b * N;
  int n0 = ch * CH;
  int n1 = min(n0 + CH, N);

  for (int i = tid; i < NBIN; i += 256) lh[i] = 0;
  float R = 0.f;
#pragma unroll
  for (int d = 0; d < 64; ++d) R += fabsf(v[d]);     // uniform
  float invW = (float)NBIN / (2.f * R);
  __syncthreads();

  // pass 1: load chunk into registers + histogram
  float4 v4[MAXJ4];
#pragma unroll
  for (int j = 0; j < MAXJ4; ++j) {
    int nn = n0 + (j * 256 + tid) * 4;
    if (j * 1024 < CH && nn < n1) {
      float4 s4 = *(const float4*)(row + nn);        // over-read past n1 is in-buffer, guarded below
      v4[j] = s4;
      float ss[4] = {s4.x, s4.y, s4.z, s4.w};
#pragma unroll
      for (int c = 0; c < 4; ++c) {
        if (nn + c < n1) {
          int bi = (int)((ss[c] + R) * invW);
          bi = bi < 0 ? 0 : (bi > NBIN - 1 ? NBIN - 1 : bi);
          atomicAdd(&lh[bi], 1);
        }
      }
    }
  }
  __syncthreads();

  if (tid < 64) {
    int s = 0;
    for (int jj = 0; jj < 64; ++jj) s += lh[tid * 64 + jj];
    part[tid] = s;
  }
  __syncthreads();
  if (tid == 0) {                  // local top threshold
    int cum = 0, c = 63;
    for (; c > 0; --c) { if (cum + part[c] >= K) break; cum += part[c]; }
    int hh = c * 64 + 63;
    for (;; --hh) { cum += lh[hh]; if (cum >= K || hh == 0) break; }
    hHi = hh;
  }
  if (tid == 1) {                  // local bottom threshold
    int cum = 0, c = 0;
    for (; c < 63; ++c) { if (cum + part[c] >= K) break; cum += part[c]; }
    int hl = c * 64;
    for (;; ++hl) { cum += lh[hl]; if (cum >= K || hl == NBIN - 1) break; }
    hLo = hl;
  }
  __syncthreads();
  int hi = hHi, lo = hLo;

  int* cP = cnt + (b * nch + ch) * 2;
  u64* cpb = candP + (size_t)(b * nch + ch) * CAPC;
  u64* cnb = candN + (size_t)(b * nch + ch) * CAPC;

  // pass 2: compact from registers
#pragma unroll
  for (int j = 0; j < MAXJ4; ++j) {
    int nn = n0 + (j * 256 + tid) * 4;
    if (j * 1024 < CH && nn < n1) {
      float ss[4] = {v4[j].x, v4[j].y, v4[j].z, v4[j].w};
#pragma unroll
      for (int c = 0; c < 4; ++c) {
        if (nn + c < n1) {
          float s = ss[c];
          int bi = (int)((s + R) * invW);
          bi = bi < 0 ? 0 : (bi > NBIN - 1 ? NBIN - 1 : bi);
          if (bi >= hi) { int i = atomicAdd(&cP[0], 1); if (i < CAPC) cpb[i] = packMax(s, nn + c); }
          if (bi <= lo) { int i = atomicAdd(&cP[1], 1); if (i < CAPC) cnb[i] = packMax(s, nn + c) ^ 0xFFFFFFFFull; }
        }
      }
    }
  }
}

// ================= select phase 2: merge + exact rank =================
__global__ void __launch_bounds__(256)
merge_kernel(const int* __restrict__ cnt, const u64* __restrict__ candP,
             const u64* __restrict__ candN, int* __restrict__ out,
             int B, int K, int nch) {
  __shared__ u64 LP[NCH * CAPC], LN[NCH * CAPC];
  __shared__ int offP[NCH + 1], offN[NCH + 1];
  int tid = threadIdx.x, b = blockIdx.x;

  if (tid == 0) {
    int sp = 0, sn = 0;
    for (int c = 0; c < nch; ++c) {
      offP[c] = sp; offN[c] = sn;
      int tp = cnt[(b * nch + c) * 2];     tp = tp < CAPC ? tp : CAPC;
      int tn = cnt[(b * nch + c) * 2 + 1]; tn = tn < CAPC ? tn : CAPC;
      sp += tp; sn += tn;
    }
    offP[nch] = sp; offN[nch] = sn;
  }
  __syncthreads();

  for (int c = 0; c < nch; ++c) {
    int tp = offP[c + 1] - offP[c];
    int tn = offN[c + 1] - offN[c];
    const u64* cpb = candP + (size_t)(b * nch + c) * CAPC;
    const u64* cnb = candN + (size_t)(b * nch + c) * CAPC;
    for (int i = tid; i < tp; i += 256) LP[offP[c] + i] = cpb[i];
    for (int i = tid; i < tn; i += 256) LN[offN[c] + i] = cnb[i];
  }
  __syncthreads();

  int tP = offP[nch], tN = offN[nch];
  int* pos = out + (size_t)b * K;
  int* neg = out + (size_t)B * K + (size_t)b * K;
  for (int i = tid; i < tP; i += 256) {
    u64 key = LP[i]; int r = 0;
    for (int jj = 0; jj < tP; ++jj) r += (LP[jj] > key);
    if (r < K) pos[r] = (int)(~(unsigned)key);
  }
  for (int i = tid; i < tN; i += 256) {
    u64 key = LN[i]; int r = 0;
    for (int jj = 0; jj < tN; ++jj) r += (LN[jj] < key);
    if (r < K) neg[r] = (int)(unsigned)key;
  }
}

extern "C" void kernel_launch(void* const* d_in, const int* in_sizes, int n_in,
                              void* d_out, int out_size, void* d_ws, size_t ws_size,
                              hipStream_t stream) {
  const float* basket = (const float*)d_in[0];
  const float* item   = (const float*)d_in[1];
  const float* Wb     = (const float*)d_in[2];
  const float* Wi     = (const float*)d_in[3];
  const float* v      = (const float*)d_in[4];
  int D = in_sizes[4];           // 64
  int B = in_sizes[0] / D;       // 128
  int N = in_sizes[1] / D;       // 50000
  int K = out_size / (2 * B);    // 50

  float* scores = (float*)d_ws;                         // B*N floats = 25.6 MB
  float* ipE    = scores + (size_t)B * N;               // N*64 floats = 12.8 MB
  float* bpE    = ipE + (size_t)N * 64;                 // B*64 floats = 32 KB
  // select structures OVERLAY ipE (dead after scores_kernel)
  int* cnt   = (int*)ipE;                               // B*NCH*2 ints
  u64* candP = (u64*)(cnt + B * NCH * 2);               // B*NCH*CAPC u64
  u64* candN = candP + (size_t)B * NCH * CAPC;

  int nItemBlk = (N + 63) / 64;
  int nBasBlk  = (B + 63) / 64;
  prep_kernel<<<dim3(nItemBlk + nBasBlk), dim3(256), 0, stream>>>(basket, item, Wb, Wi, ipE, bpE, N, B, nItemBlk);

  dim3 gs((N + 255) / 256, (B + BT - 1) / BT);
  scores_kernel<<<gs, dim3(256), 0, stream>>>(ipE, bpE, v, scores, N, B);

  // chunking: CH multiple of 1024, nch <= NCH
  int CH = ((N + NCH - 1) / NCH + 1023) & ~1023;
  int nch = (N + CH - 1) / CH;
  hipMemsetAsync(cnt, 0, (size_t)B * NCH * 2 * sizeof(int), stream);
  select1_kernel<<<dim3(nch, B), dim3(256), 0, stream>>>(scores, v, cnt, candP, candN, N, CH, nch, K);
  merge_kernel<<<dim3(B), dim3(256), 0, stream>>>(cnt, candP, candN, (int*)d_out, B, K, nch);
}

// Round 9
// 90.157 us; speedup vs baseline: 1.4701x; 1.4701x over previous
//
#include <hip/hip_runtime.h>

typedef unsigned long long u64;

#define CSC 2.8853900817779268f   // 2*log2(e): tanh(x) = 1 - 2/(exp2(x*CSC)+1)
#define NBIN 4096
#define CAP  256
#define BT   8
#define MAXJ 16                   // select supports N <= 16*4096

// ---------- sortable key packing ----------
__device__ __forceinline__ unsigned ord32(float f) {
  unsigned u = __float_as_uint(f);
  return (u & 0x80000000u) ? ~u : (u | 0x80000000u);
}
// max-key: descending score, ties -> ascending index (jax.lax.top_k semantics)
__device__ __forceinline__ u64 packMax(float f, int n) {
  return ((u64)ord32(f) << 32) | (unsigned)(~(unsigned)n);
}

// ================= prep: 4x4 register-tiled projection (r7, unchanged) =================
__global__ void __launch_bounds__(256)
prep_kernel(const float* __restrict__ basket, const float* __restrict__ item,
            const float* __restrict__ Wb, const float* __restrict__ Wi,
            float* __restrict__ ipE, float* __restrict__ bpE,
            int N, int B, int nItemBlk) {
  __shared__ float itS[64][64];   // [e][row]
  __shared__ float WT[64][64];    // [e][d]
  int tid = threadIdx.x;

  bool isBasket = (blockIdx.x >= nItemBlk);
  const float* src = isBasket ? basket : item;
  const float* W   = isBasket ? Wb : Wi;
  float* dst       = isBasket ? bpE : ipE;
  int r0   = isBasket ? (blockIdx.x - nItemBlk) * 64 : blockIdx.x * 64;
  int rMax = isBasket ? B : N;

  {
    int r = tid & 63, ec = (tid >> 6) * 16;
    const float4* sp = (const float4*)(src + (size_t)(r0 + r) * 64 + ec);
    bool ok = (r0 + r) < rMax;
#pragma unroll
    for (int q = 0; q < 4; ++q) {
      float4 t = ok ? sp[q] : make_float4(0.f, 0.f, 0.f, 0.f);
      itS[ec + 4 * q + 0][r] = t.x;
      itS[ec + 4 * q + 1][r] = t.y;
      itS[ec + 4 * q + 2][r] = t.z;
      itS[ec + 4 * q + 3][r] = t.w;
    }
    const float4* wp = (const float4*)(W + (size_t)r * 64 + ec);
#pragma unroll
    for (int q = 0; q < 4; ++q) {
      float4 t = wp[q];
      WT[ec + 4 * q + 0][r] = t.x;
      WT[ec + 4 * q + 1][r] = t.y;
      WT[ec + 4 * q + 2][r] = t.z;
      WT[ec + 4 * q + 3][r] = t.w;
    }
  }
  __syncthreads();

  int ti = tid & 15, td = tid >> 4;
  float acc[4][4];
#pragma unroll
  for (int i = 0; i < 4; ++i)
#pragma unroll
    for (int j = 0; j < 4; ++j) acc[i][j] = 0.f;

#pragma unroll 8
  for (int e = 0; e < 64; ++e) {
    float4 ri = *(const float4*)&itS[e][4 * ti];
    float4 wd = *(const float4*)&WT[e][4 * td];
    float rr[4] = {ri.x, ri.y, ri.z, ri.w};
    float ww[4] = {wd.x, wd.y, wd.z, wd.w};
#pragma unroll
    for (int i = 0; i < 4; ++i)
#pragma unroll
      for (int j = 0; j < 4; ++j) acc[i][j] = fmaf(rr[i], ww[j], acc[i][j]);
  }

#pragma unroll
  for (int i = 0; i < 4; ++i) {
    int gr = r0 + 4 * ti + i;
    if (gr < rMax) {
      float4 o;
      o.x = __builtin_amdgcn_exp2f(acc[i][0] * CSC);
      o.y = __builtin_amdgcn_exp2f(acc[i][1] * CSC);
      o.z = __builtin_amdgcn_exp2f(acc[i][2] * CSC);
      o.w = __builtin_amdgcn_exp2f(acc[i][3] * CSC);
      *(float4*)(dst + (size_t)gr * 64 + 4 * td) = o;
    }
  }
}

// ================= scores: 4-term rational, f32 accumulation, BT=8 =================
__global__ void __launch_bounds__(256)
scores_kernel(const float* __restrict__ ipE, const float* __restrict__ bpE,
              const float* __restrict__ v, float* __restrict__ scores, int N, int B) {
  int tid = threadIdx.x;
  int b0 = blockIdx.y * BT;
  if (b0 > B - BT) b0 = B - BT;              // duplicate-safe clamp
  int n = blockIdx.x * 256 + tid;
  if (n >= N) return;

  float ei[64];
  const float4* p = (const float4*)(ipE + (size_t)n * 64);
#pragma unroll
  for (int i = 0; i < 16; ++i) {
    float4 t = p[i];
    ei[4 * i] = t.x; ei[4 * i + 1] = t.y; ei[4 * i + 2] = t.z; ei[4 * i + 3] = t.w;
  }

  float svf;
  {
    double sv = 0.0;
#pragma unroll
    for (int d = 0; d < 64; ++d) sv += (double)v[d]; // uniform -> s_load
    svf = (float)sv;
  }

#pragma unroll 4
  for (int b = 0; b < BT; ++b) {
    const float* eb = bpE + (size_t)(b0 + b) * 64;   // uniform -> s_load
    float acc = 0.f;
#pragma unroll
    for (int g = 0; g < 8; ++g) {
#pragma unroll
      for (int h = 0; h < 2; ++h) {                  // 4-term rational subgroups
        int q0 = g * 8 + h * 4;
        float x0 = fmaf(eb[q0 + 0], ei[q0 + 0], 1.0f);
        float x1 = fmaf(eb[q0 + 1], ei[q0 + 1], 1.0f);
        float x2 = fmaf(eb[q0 + 2], ei[q0 + 2], 1.0f);
        float x3 = fmaf(eb[q0 + 3], ei[q0 + 3], 1.0f);
        float p01 = x0 * x1, p23 = x2 * x3;
        float den = p01 * p23;
        float n01 = v[q0 + 0] * x1;
        n01 = fmaf(v[q0 + 1], x0, n01);
        float n23 = v[q0 + 2] * x3;
        n23 = fmaf(v[q0 + 3], x2, n23);
        float num = n01 * p23;
        num = fmaf(n23, p01, num);
        float r = __builtin_amdgcn_rcpf(den);        // 1 rcp per 4 terms
        acc = fmaf(num, r, acc);                     // f32 accumulation
      }
    }
    scores[(size_t)(b0 + b) * N + n] = fmaf(-2.0f, acc, svf);
  }
}

// ================= select: whole pipeline in ONE kernel (r7, unchanged) =================
__global__ void __launch_bounds__(1024)
select_kernel(const float* __restrict__ scores, const float* __restrict__ v,
              int* __restrict__ out, int N, int B, int K) {
  __shared__ int lh[NBIN];
  __shared__ int part[64];
  __shared__ u64 candP[CAP], candN[CAP];
  __shared__ int cntP, cntN, hHi, hLo;
  int tid = threadIdx.x, b = blockIdx.x;
  const float* row = scores + (size_t)b * N;

  for (int i = tid; i < NBIN; i += 1024) lh[i] = 0;
  if (tid == 0) { cntP = 0; cntN = 0; }

  // |score| < R = sum|v_d| strictly (|tanh|<1) -> linear bins over [-R, R]
  float R = 0.f;
#pragma unroll
  for (int d = 0; d < 64; ++d) R += fabsf(v[d]);     // uniform
  float invW = (float)NBIN / (2.f * R);
  __syncthreads();

  // pass 1: load into REGISTERS + histogram
  float4 v4[MAXJ];
#pragma unroll
  for (int j = 0; j < MAXJ; ++j) {
    int f4 = j * 1024 + tid;
    if (j * 4096 < N && f4 * 4 < N) {
      float4 s4 = *(const float4*)(row + (size_t)f4 * 4);
      v4[j] = s4;
      int n0 = f4 * 4;
      float ss[4] = {s4.x, s4.y, s4.z, s4.w};
#pragma unroll
      for (int c = 0; c < 4; ++c) {
        if (n0 + c < N) {
          int bi = (int)((ss[c] + R) * invW);
          bi = bi < 0 ? 0 : (bi > NBIN - 1 ? NBIN - 1 : bi);
          atomicAdd(&lh[bi], 1);
        }
      }
    }
  }
  __syncthreads();

  if (tid < 64) {                  // 64-bin chunk sums
    int s = 0;
    for (int jj = 0; jj < 64; ++jj) s += lh[tid * 64 + jj];
    part[tid] = s;
  }
  __syncthreads();
  if (tid == 0) {                  // top threshold bin
    int cum = 0, c = 63;
    for (; c > 0; --c) { if (cum + part[c] >= K) break; cum += part[c]; }
    int hh = c * 64 + 63;
    for (;; --hh) { cum += lh[hh]; if (cum >= K || hh == 0) break; }
    hHi = hh;
  }
  if (tid == 1) {                  // bottom threshold bin
    int cum = 0, c = 0;
    for (; c < 63; ++c) { if (cum + part[c] >= K) break; cum += part[c]; }
    int hl = c * 64;
    for (;; ++hl) { cum += lh[hl]; if (cum >= K || hl == NBIN - 1) break; }
    hLo = hl;
  }
  __syncthreads();
  int hi = hHi, lo = hLo;

  // pass 2: compact from registers (no memory re-read)
#pragma unroll
  for (int j = 0; j < MAXJ; ++j) {
    int f4 = j * 1024 + tid;
    if (j * 4096 < N && f4 * 4 < N) {
      int n0 = f4 * 4;
      float ss[4] = {v4[j].x, v4[j].y, v4[j].z, v4[j].w};
#pragma unroll
      for (int c = 0; c < 4; ++c) {
        if (n0 + c < N) {
          float s = ss[c];
          int bi = (int)((s + R) * invW);
          bi = bi < 0 ? 0 : (bi > NBIN - 1 ? NBIN - 1 : bi);
          if (bi >= hi) { int i = atomicAdd(&cntP, 1); if (i < CAP) candP[i] = packMax(s, n0 + c); }
          if (bi <= lo) { int i = atomicAdd(&cntN, 1); if (i < CAP) candN[i] = packMax(s, n0 + c) ^ 0xFFFFFFFFull; }
        }
      }
    }
  }
  __syncthreads();

  // exact rank, O(C^2); keys unique -> ranks unique & complete
  int tP = cntP < CAP ? cntP : CAP;
  int tN = cntN < CAP ? cntN : CAP;
  int* pos = out + (size_t)b * K;
  int* neg = out + (size_t)B * K + (size_t)b * K;
  for (int i = tid; i < tP; i += 1024) {
    u64 key = candP[i]; int r = 0;
    for (int jj = 0; jj < tP; ++jj) r += (candP[jj] > key);
    if (r < K) pos[r] = (int)(~(unsigned)key);
  }
  for (int i = tid; i < tN; i += 1024) {
    u64 key = candN[i]; int r = 0;
    for (int jj = 0; jj < tN; ++jj) r += (candN[jj] < key);
    if (r < K) neg[r] = (int)(unsigned)key;
  }
}

extern "C" void kernel_launch(void* const* d_in, const int* in_sizes, int n_in,
                              void* d_out, int out_size, void* d_ws, size_t ws_size,
                              hipStream_t stream) {
  const float* basket = (const float*)d_in[0];
  const float* item   = (const float*)d_in[1];
  const float* Wb     = (const float*)d_in[2];
  const float* Wi     = (const float*)d_in[3];
  const float* v      = (const float*)d_in[4];
  int D = in_sizes[4];           // 64
  int B = in_sizes[0] / D;       // 128
  int N = in_sizes[1] / D;       // 50000
  int K = out_size / (2 * B);    // 50

  float* scores = (float*)d_ws;                         // B*N floats = 25.6 MB
  float* ipE    = scores + (size_t)B * N;               // N*64 floats = 12.8 MB
  float* bpE    = ipE + (size_t)N * 64;                 // B*64 floats = 32 KB

  int nItemBlk = (N + 63) / 64;
  int nBasBlk  = (B + 63) / 64;
  prep_kernel<<<dim3(nItemBlk + nBasBlk), dim3(256), 0, stream>>>(basket, item, Wb, Wi, ipE, bpE, N, B, nItemBlk);

  dim3 gs((N + 255) / 256, (B + BT - 1) / BT);
  scores_kernel<<<gs, dim3(256), 0, stream>>>(ipE, bpE, v, scores, N, B);

  select_kernel<<<dim3(B), dim3(1024), 0, stream>>>(scores, v, (int*)d_out, N, B, K);
}